// Round 1
// 117.214 us; speedup vs baseline: 1.0020x; 1.0020x over previous
//
#include <hip/hip_runtime.h>
#include <math.h>

#define L_LEN  262144          // L = 2^18 = 512*512
#define NST    64
#define TPB    256
#define TSTR   544             // padded row stride (float2) for transpose staging:
                               // 544*8B = 4352B = 17 x 256B  -> odd granule step,
                               // breaks 4KB power-of-2 channel aliasing on scatters
#define PI2F   6.2831853071795864769f
#define PIF    3.1415926535897932385f

__device__ inline float2 cmul(float2 a, float2 b) {
    return make_float2(a.x*b.x - a.y*b.y, a.x*b.y + a.y*b.x);
}

// NF independent length-M FFTs in LDS, radix-4 Stockham + final radix-2.
// Layout buf[f*M+i]; natural in/out; sgn=-1 fwd, +1 inv (unscaled).
// Starts and ends with __syncthreads().
template<int M, int NF>
__device__ float2* lds_fft_r4(float2* b0, float2* b1, float sgn) {
    float2* src = b0; float2* dst = b1;
    int Ns = 1;
    while (Ns * 4 <= M) {
        __syncthreads();
        const int NB = NF * (M / 4);
        for (int bi = threadIdx.x; bi < NB; bi += TPB) {
            int f = bi / (M / 4);
            int j = bi & (M / 4 - 1);
            int r = j & (Ns - 1);
            const float2* s = src + f * M;
            float2 x0 = s[j];
            float2 x1 = s[j +     (M/4)];
            float2 x2 = s[j + 2 * (M/4)];
            float2 x3 = s[j + 3 * (M/4)];
            float ang = sgn * PI2F * ((float)r / (float)(4 * Ns));
            float sn, cs; __sincosf(ang, &sn, &cs);
            float2 w1 = make_float2(cs, sn);
            float2 w2 = cmul(w1, w1);
            float2 w3 = cmul(w2, w1);
            x1 = cmul(x1, w1); x2 = cmul(x2, w2); x3 = cmul(x3, w3);
            float2 t0 = make_float2(x0.x + x2.x, x0.y + x2.y);
            float2 t1 = make_float2(x0.x - x2.x, x0.y - x2.y);
            float2 t2 = make_float2(x1.x + x3.x, x1.y + x3.y);
            float2 t3 = make_float2(x1.x - x3.x, x1.y - x3.y);
            float2* d = dst + f * M + ((j - r) << 2) + r;
            d[0]      = make_float2(t0.x + t2.x, t0.y + t2.y);
            d[Ns]     = make_float2(t1.x - sgn * t3.y, t1.y + sgn * t3.x);
            d[2 * Ns] = make_float2(t0.x - t2.x, t0.y - t2.y);
            d[3 * Ns] = make_float2(t1.x + sgn * t3.y, t1.y - sgn * t3.x);
        }
        float2* t = src; src = dst; dst = t;
        Ns <<= 2;
    }
    if (Ns < M) {
        __syncthreads();
        const int NB = NF * (M / 2);
        for (int bi = threadIdx.x; bi < NB; bi += TPB) {
            int f = bi / (M / 2);
            int j = bi & (M / 2 - 1);
            const float2* s = src + f * M;
            float2 a = s[j];
            float2 b = s[j + M / 2];
            float ang = sgn * PI2F * ((float)j / (float)M);
            float sn, cs; __sincosf(ang, &sn, &cs);
            float2 wb = make_float2(cs * b.x - sn * b.y, cs * b.y + sn * b.x);
            float2* d = dst + f * M + j;
            d[0]     = make_float2(a.x + wb.x, a.y + wb.y);
            d[M / 2] = make_float2(a.x - wb.x, a.y - wb.y);
        }
        float2* t = src; src = dst; dst = t;
    }
    __syncthreads();
    return src;
}

// Staging arrays: transpose-staged ones are [row*TSTR + col] (padded),
// row-contiguous ones (Acm, Ue, Uo) stay [row<<9 + col].

// ---- kI: blocks 0..255: atroots (4 pts/thread, LDS pole tables read once
//          per pole and reused x4) + store Acm + ifft-L pass1 -> T_K.
//          blocks 256..511: u & u*tw fwd pass1 (NF=4) -> T_U, T_Uo.
__global__ __launch_bounds__(TPB) void kI(
    const float* __restrict__ u,
    const float* __restrict__ Lre, const float* __restrict__ Lim,
    const float* __restrict__ Pre, const float* __restrict__ Pim,
    const float* __restrict__ Bre, const float* __restrict__ Bim,
    const float* __restrict__ Cri, const float* __restrict__ lstp,
    float2* __restrict__ Acm, float2* __restrict__ T_K,
    float2* __restrict__ T_U, float2* __restrict__ T_Uo)
{
    __shared__ float2 b0[2048], b1[2048];
    __shared__ float4 cA[NST], cB[NST], cC[NST], cD[NST];
    const int t = threadIdx.x, bx = blockIdx.x;
    const int c0 = (bx & 255) << 1;
    const float invL = 1.0f / (float)L_LEN;
    if (bx < 256) {
        if (t < NST) {
            float lr = Lre[t], li = Lim[t];
            float pr = Pre[t], pi = Pim[t];
            float br = Bre[t], bi = Bim[t];
            float cr = Cri[2*t], ci = Cri[2*t+1];
            float dx = -lr;
            float v00x = cr*br + ci*bi, v00y = cr*bi - ci*br;   // conj(C)*B
            float v01x = cr*pr + ci*pi, v01y = cr*pi - ci*pr;   // conj(C)*P
            float v10x = pr*br + pi*bi, v10y = pr*bi - pi*br;   // conj(P)*B
            float v11x = pr*pr + pi*pi;                         // conj(P)*P
            cA[t] = make_float4(li, dx*dx, dx*v11x, -v11x);
            cB[t] = make_float4(dx*v00x, v00y, dx*v00y, -v00x);
            cC[t] = make_float4(dx*v01x, v01y, dx*v01y, -v01x);
            cD[t] = make_float4(dx*v10x, v10y, dx*v10y, -v10x);
        }
        __syncthreads();
        float G2 = 2.0f / expf(lstp[0]);
        float tn[4], gi[4], acc[4][8];
        #pragma unroll
        for (int p = 0; p < 4; ++p) {
            int i = t + (p << 8);
            int f = i >> 9, e = i & 511;
            int m = (c0 + f) + (e << 9);
            float h = PIF * ((float)m * invL);
            float sn, cs; __sincosf(h, &sn, &cs);
            float tv = sn * __frcp_rn(cs);
            tv = fminf(fmaxf(tv, -1e7f), 1e7f);  // pole guard (m=L/2: cos==0)
            tn[p] = tv; gi[p] = G2 * tv;
            #pragma unroll
            for (int q = 0; q < 8; ++q) acc[p][q] = 0.f;
        }
        #pragma unroll 2
        for (int n = 0; n < NST; ++n) {
            float4 a = cA[n], b = cB[n], cc = cC[n], d = cD[n];
            #pragma unroll
            for (int p = 0; p < 4; ++p) {
                float dy   = gi[p] - a.x;
                float iv   = __frcp_rn(fmaf(dy, dy, a.y));
                float ivdy = iv * dy;
                acc[p][6] = fmaf(iv, a.z, acc[p][6]);
                acc[p][7] = fmaf(ivdy, a.w, acc[p][7]);
                acc[p][0] = fmaf(iv, b.x,  fmaf(ivdy, b.y,  acc[p][0]));
                acc[p][1] = fmaf(iv, b.z,  fmaf(ivdy, b.w,  acc[p][1]));
                acc[p][2] = fmaf(iv, cc.x, fmaf(ivdy, cc.y, acc[p][2]));
                acc[p][3] = fmaf(iv, cc.z, fmaf(ivdy, cc.w, acc[p][3]));
                acc[p][4] = fmaf(iv, d.x,  fmaf(ivdy, d.y,  acc[p][4]));
                acc[p][5] = fmaf(iv, d.z,  fmaf(ivdy, d.w,  acc[p][5]));
            }
        }
        #pragma unroll
        for (int p = 0; p < 4; ++p) {
            int i = t + (p << 8);
            int f = i >> 9, e = i & 511;
            float ax = 1.f + acc[p][6], ay = acc[p][7];
            float im = 1.f / (ax*ax + ay*ay);
            float tx = acc[p][2]*acc[p][4] - acc[p][3]*acc[p][5];
            float ty = acc[p][2]*acc[p][5] + acc[p][3]*acc[p][4];
            float wx = acc[p][0] - (tx*ax + ty*ay) * im;
            float wy = acc[p][1] - (ty*ax - tx*ay) * im;
            float2 A = make_float2(wx - tn[p]*wy, wy + tn[p]*wx); // (1+i*tan)*w
            Acm[((c0 + f) << 9) + e] = A;                // contiguous store
            b0[i] = A;
        }
        float2* r = lds_fft_r4<512, 2>(b0, b1, +1.f);
        for (int i = t; i < 1024; i += TPB) {
            int f = i & 1, k = i >> 1;
            int c = c0 + f;
            float ang = PI2F * ((float)(c * k) * invL);
            float sn, cs; __sincosf(ang, &sn, &cs);
            T_K[k * TSTR + c] = cmul(make_float2(cs, sn), r[(f << 9) + k]);
        }
    } else {
        for (int i = t; i < 1024; i += TPB) {
            int f = i & 1, e = i >> 1;
            int n = (c0 + f) + (e << 9);
            float uv = u[n];                             // 8B-paired gather
            float sn, cs; __sincosf(PIF * ((float)n * invL), &sn, &cs);
            b0[(f << 9) + e]       = make_float2(uv, 0.f);           // u
            b0[((2 + f) << 9) + e] = make_float2(uv * cs, -uv * sn); // u*tw
        }
        float2* r = lds_fft_r4<512, 4>(b0, b1, -1.f);
        for (int i = t; i < 2048; i += TPB) {
            int f = i & 1, k = (i >> 1) & 511, v = i >> 10;
            int c = c0 + f;
            float ang = -PI2F * ((float)(c * k) * invL);
            float sn, cs; __sincosf(ang, &sn, &cs);
            float2 val = cmul(make_float2(cs, sn), r[(((v << 1) + f) << 9) + k]);
            if (v == 0) T_U [k * TSTR + c] = val;
            else        T_Uo[k * TSTR + c] = val;
        }
    }
}

// ---- kII: blocks 0..255: T_K pass2 -> K -> K*tw -> fwd pass1 -> T_Ko
//           blocks 256..511: pass2 of T_U,T_Uo -> Ue, Uo
__global__ __launch_bounds__(TPB) void kII(
    const float2* __restrict__ T_K, const float2* __restrict__ T_U,
    const float2* __restrict__ T_Uo,
    float2* __restrict__ T_Ko, float2* __restrict__ Ue, float2* __restrict__ Uo)
{
    __shared__ float2 b0[2048], b1[2048];
    const int t = threadIdx.x, bx = blockIdx.x;
    const int c0 = (bx & 255) << 1;
    const float invL = 1.0f / (float)L_LEN;
    if (bx < 256) {
        for (int i = t; i < 1024; i += TPB)
            b0[i] = T_K[(c0 + (i >> 9)) * TSTR + (i & 511)];   // contiguous
        float2* r = lds_fft_r4<512, 2>(b0, b1, +1.f);
        float2* o = (r == b0) ? b1 : b0;
        for (int i = t; i < 1024; i += TPB) {
            int f = i >> 9, o1 = i & 511;
            int n = (c0 + f) + (o1 << 9);
            float K = r[i].x * invL;                       // Re(ifft)/L
            float sn, cs; __sincosf(PIF * ((float)n * invL), &sn, &cs);
            o[i] = make_float2(K * cs, -K * sn);           // K * e^{-i pi n/L}
        }
        float2* r2 = lds_fft_r4<512, 2>(o, r, -1.f);
        for (int i = t; i < 1024; i += TPB) {
            int f = i & 1, k = i >> 1;
            int c = c0 + f;
            float ang = -PI2F * ((float)(c * k) * invL);
            float sn, cs; __sincosf(ang, &sn, &cs);
            T_Ko[k * TSTR + c] = cmul(make_float2(cs, sn), r2[(f << 9) + k]);
        }
    } else {
        for (int i = t; i < 2048; i += TPB) {
            int v = i >> 10, f = (i >> 9) & 1, e = i & 511;
            const float2* Tin = v ? T_Uo : T_U;
            b0[i] = Tin[(c0 + f) * TSTR + e];              // contiguous
        }
        float2* r = lds_fft_r4<512, 4>(b0, b1, -1.f);
        for (int i = t; i < 2048; i += TPB) {
            int v = i >> 10, f = (i >> 9) & 1, k2 = i & 511;
            float2* Xo = v ? Uo : Ue;
            Xo[((c0 + f) << 9) + k2] = r[i];               // contiguous
        }
    }
}

// ---- kIII: grid 512, one row kc/block: Ko pass2 (NF=1) + Ve=Ue*A, Vo=Uo*Ko
//            + inv pass1 (NF=2) -> T_Ve, T_Vo
__global__ __launch_bounds__(TPB) void kIII(
    const float2* __restrict__ T_Ko, const float2* __restrict__ Ue,
    const float2* __restrict__ Uo, const float2* __restrict__ Acm,
    float2* __restrict__ T_Ve, float2* __restrict__ T_Vo)
{
    __shared__ float2 b0[1024], b1[1024];
    const int t = threadIdx.x, kc = blockIdx.x;
    const float invL = 1.0f / (float)L_LEN;
    for (int i = t; i < 512; i += TPB)
        b0[i] = T_Ko[kc * TSTR + i];                        // contiguous
    float2* r = lds_fft_r4<512, 1>(b0, b1, -1.f);           // Ko[kc+512*k2]
    float2* o = (r == b0) ? b1 : b0;
    for (int i = t; i < 512; i += TPB) {
        float2 ko = r[i];
        float2 ue = Ue [(kc << 9) + i];                     // contiguous
        float2 uo = Uo [(kc << 9) + i];
        float2 av = Acm[(kc << 9) + i];
        o[i]       = cmul(ue, av);   // Ve (Ue Hermitian => Herm(A) not needed)
        o[i + 512] = cmul(uo, ko);   // Vo
    }
    float2* r2 = lds_fft_r4<512, 2>(o, r, +1.f);
    for (int i = t; i < 1024; i += TPB) {
        int v = i >> 9, k = i & 511;
        float ang = PI2F * ((float)(kc * k) * invL);
        float sn, cs; __sincosf(ang, &sn, &cs);
        float2 val = cmul(make_float2(cs, sn), r2[(v << 9) + k]);
        if (v == 0) T_Ve[k * TSTR + kc] = val;
        else        T_Vo[k * TSTR + kc] = val;
    }
}

// ---- kIV: grid 512, one row k/block: inv pass2 (NF=2) + combine + D*u + out
__global__ __launch_bounds__(TPB) void kIV(
    const float2* __restrict__ T_Ve, const float2* __restrict__ T_Vo,
    const float* __restrict__ u, const float* __restrict__ Dp,
    float* __restrict__ out)
{
    __shared__ float2 b0[1024], b1[1024];
    const int t = threadIdx.x, k = blockIdx.x;
    const float invL = 1.0f / (float)L_LEN;
    for (int i = t; i < 512; i += TPB) {
        b0[i]       = T_Ve[k * TSTR + i];                   // contiguous
        b0[i + 512] = T_Vo[k * TSTR + i];
    }
    float2* r = lds_fft_r4<512, 2>(b0, b1, +1.f);           // [0,512)=yE, rest yO
    const float sc = 0.5f * invL;                           // 1/(2L)
    const float D = Dp[0];
    for (int o1 = t; o1 < 512; o1 += TPB) {
        int n = k + (o1 << 9);
        float sn, cs; __sincosf(PIF * ((float)n * invL), &sn, &cs);
        float2 yE = r[o1];
        float2 yO = r[o1 + 512];
        // y = (yE.re + Re(e^{+i pi n/L} * yO)) / (2L) + D*u
        out[n] = fmaf(D, u[n], (yE.x + cs * yO.x - sn * yO.y) * sc);
    }
}

extern "C" void kernel_launch(void* const* d_in, const int* in_sizes, int n_in,
                              void* d_out, int out_size, void* d_ws, size_t ws_size,
                              hipStream_t stream) {
    const float* u    = (const float*)d_in[0];
    const float* Lre  = (const float*)d_in[1];
    const float* Lim  = (const float*)d_in[2];
    const float* Pre  = (const float*)d_in[3];
    const float* Pim  = (const float*)d_in[4];
    const float* Bre  = (const float*)d_in[5];
    const float* Bim  = (const float*)d_in[6];
    const float* Cri  = (const float*)d_in[7];
    const float* Dp   = (const float*)d_in[8];
    const float* lstp = (const float*)d_in[9];
    float* out = (float*)d_out;

    // Workspace layout (~19.7 MB total; ws is 256 MiB per harness poison fill):
    //  unpadded 512-stride arrays: 2 MB each; padded TSTR arrays: 544*512*8 = 0x220000 each
    char* ws = (char*)d_ws;
    float2* Acm  = (float2*)(ws);                    // 512-stride
    float2* Ue   = (float2*)(ws + 0x200000);         // 512-stride
    float2* Uo   = (float2*)(ws + 0x400000);         // 512-stride
    float2* T_K  = (float2*)(ws + 0x600000);         // TSTR-stride
    float2* T_U  = (float2*)(ws + 0x820000);         // TSTR-stride
    float2* T_Uo = (float2*)(ws + 0xA40000);         // TSTR-stride
    float2* T_Ko = (float2*)(ws + 0xC60000);         // TSTR-stride
    float2* T_Ve = (float2*)(ws + 0xE80000);         // TSTR-stride
    float2* T_Vo = (float2*)(ws + 0x10A0000);        // TSTR-stride

    kI  <<<512, TPB, 0, stream>>>(u, Lre,Lim,Pre,Pim,Bre,Bim,Cri,lstp,
                                  Acm, T_K, T_U, T_Uo);
    kII <<<512, TPB, 0, stream>>>(T_K, T_U, T_Uo, T_Ko, Ue, Uo);
    kIII<<<512, TPB, 0, stream>>>(T_Ko, Ue, Uo, Acm, T_Ve, T_Vo);
    kIV <<<512, TPB, 0, stream>>>(T_Ve, T_Vo, u, Dp, out);
}